// Round 4
// baseline (84.787 us; speedup 1.0000x reference)
//
#include <hip/hip_runtime.h>
#include <math.h>

#define B_  16
#define T_  16
#define N_  256
#define D_  384
#define Q_  384
#define K_  16
#define BT_ (B_ * T_)

// No d_ws anywhere: the harness's workspace poison-fill (402 MB) lands in the
// timed graph (R2 lesson). d_out (= BT_*Q_ floats = BT_*D_ floats) is used as
// the inter-kernel scratch: qp -> od -> final out, each block touching only
// its own rows, read-before-write, stream-ordered.

// ---------------------------------------------------------------------------
// Kernel 1: qp[bt] = queries[bt] @ W_in + b_in   (qp written into io=d_out)
// 64 blocks x 384 threads, 4 bt rows per block.
// ---------------------------------------------------------------------------
__global__ __launch_bounds__(384)
void qproj_kernel(const float* __restrict__ queries,  // [BT_, Q_]
                  const float* __restrict__ W_in,     // [Q_, D_]
                  const float* __restrict__ b_in,     // [D_]
                  float* __restrict__ io)             // [BT_, D_] (d_out)
{
    const int bt0 = blockIdx.x * 4;
    const int tid = threadIdx.x;            // 0..383 == output d

    __shared__ float s_q[4][Q_];
    #pragma unroll
    for (int r = 0; r < 4; ++r)
        s_q[r][tid] = queries[(size_t)(bt0 + r) * Q_ + tid];
    __syncthreads();

    const float bi = b_in[tid];
    float acc[4] = {bi, bi, bi, bi};

    #pragma unroll 4
    for (int q = 0; q < Q_; ++q) {
        const float w = W_in[(size_t)q * D_ + tid];
        #pragma unroll
        for (int r = 0; r < 4; ++r) acc[r] += s_q[r][q] * w;
    }
    #pragma unroll
    for (int r = 0; r < 4; ++r)
        io[(size_t)(bt0 + r) * D_ + tid] = acc[r];
}

// ---------------------------------------------------------------------------
// Kernel 2: per (b,t): scores -> softmax -> exact top-K -> weighted patch sum
// 256 blocks x 1024 threads. Reads own qp row from io, writes od over it.
// ---------------------------------------------------------------------------
__global__ __launch_bounds__(1024)
void scores_topk_kernel(const float* __restrict__ patch,  // [BT_, N_, D_]
                        float* __restrict__ io)           // [BT_, D_] qp->od
{
    const int bt   = blockIdx.x;
    const int tid  = threadIdx.x;       // 0..1023
    const int lane = tid & 63;
    const int wave = tid >> 6;          // 0..15

    __shared__ float s_qp[D_];
    __shared__ float s_sc[N_];
    __shared__ int   s_cnt4[N_][4];     // rank partial counts
    __shared__ float s_red[4];
    __shared__ float s_red2[4][2];
    __shared__ float s_w[K_];
    __shared__ int   s_ix[K_];
    __shared__ float s_part[2 * D_];

    const float* __restrict__ ptile = patch + (size_t)bt * N_ * D_;

    if (tid < D_) s_qp[tid] = io[(size_t)bt * D_ + tid];
    __syncthreads();

    // ---- scores: 16 waves x 4 rows (16-lane groups) x 4 iters ----
    {
        const int g  = lane >> 4;       // 0..3
        const int sl = lane & 15;
        const float4* s_qp4 = reinterpret_cast<const float4*>(s_qp);
        #pragma unroll
        for (int it = 0; it < N_ / 64; ++it) {
            const int n = it * 64 + wave * 4 + g;
            const float* prow = ptile + (size_t)n * D_;
            float p = 0.f;
            #pragma unroll
            for (int c = 0; c < 6; ++c) {
                const float4 a = *reinterpret_cast<const float4*>(prow + c * 64 + 4 * sl);
                const float4 b = s_qp4[c * 16 + sl];
                p += a.x * b.x + a.y * b.y + a.z * b.z + a.w * b.w;
            }
            #pragma unroll
            for (int off = 8; off; off >>= 1)
                p += __shfl_xor(p, off, 16);
            if (sl == 0) s_sc[n] = p;   // TEMP == 1
        }
    }
    __syncthreads();

    // ---- max (threads<256) + rank partial counts (all 1024 threads) ----
    if (tid < N_) {
        float v = s_sc[tid];
        #pragma unroll
        for (int off = 32; off; off >>= 1) v = fmaxf(v, __shfl_xor(v, off));
        if (lane == 0) s_red[wave] = v;
    }
    {
        const int i   = tid >> 2;       // 0..255
        const int sub = tid & 3;        // j range [sub*64, sub*64+64)
        const float si = s_sc[i];
        int c = 0;
        #pragma unroll 8
        for (int j = sub * 64; j < sub * 64 + 64; ++j) {
            const float sj = s_sc[j];
            c += (int)(sj > si) | ((int)(sj == si) & (int)(j < i));
        }
        s_cnt4[i][sub] = c;
    }
    __syncthreads();

    // ---- e, Z, SK (threads<256) ----
    float e = 0.f;
    int   cnt = N_;
    if (tid < N_) {
        const float mx = fmaxf(fmaxf(s_red[0], s_red[1]), fmaxf(s_red[2], s_red[3]));
        cnt = s_cnt4[tid][0] + s_cnt4[tid][1] + s_cnt4[tid][2] + s_cnt4[tid][3];
        e = __expf(s_sc[tid] - mx);

        float z  = e;
        float sk = (cnt < K_) ? e : 0.f;
        #pragma unroll
        for (int off = 32; off; off >>= 1) {
            z  += __shfl_xor(z, off);
            sk += __shfl_xor(sk, off);
        }
        if (lane == 0) { s_red2[wave][0] = z; s_red2[wave][1] = sk; }
    }
    __syncthreads();

    // weight_i = softmax_i / (sum_topk + EPS) = e_i / (SK + EPS*Z)
    {
        const float Z  = s_red2[0][0] + s_red2[1][0] + s_red2[2][0] + s_red2[3][0];
        const float SK = s_red2[0][1] + s_red2[1][1] + s_red2[2][1] + s_red2[3][1];
        const float inv = 1.f / (SK + 1e-8f * Z);
        if (tid < N_ && cnt < K_) {
            s_ix[cnt] = tid;
            s_w[cnt]  = e * inv;
        }
    }
    __syncthreads();

    // ---- weighted sum over K rows: 768 threads, 2-way split over j ----
    if (tid < 2 * D_) {
        const int half = tid >= D_;
        const int d    = tid - half * D_;
        const int j0   = half * (K_ / 2);
        float acc = 0.f;
        #pragma unroll
        for (int j = j0; j < j0 + K_ / 2; ++j)
            acc += s_w[j] * ptile[(size_t)s_ix[j] * D_ + d];
        s_part[tid] = acc;
    }
    __syncthreads();
    if (tid < D_)
        io[(size_t)bt * D_ + tid] = s_part[tid] + s_part[tid + D_];
}

// ---------------------------------------------------------------------------
// Kernel 3: out[bt] = od[bt] @ W_out + b_out   (od read from io, out -> io)
// 64 blocks x 384 threads, 4 rows per block.
// ---------------------------------------------------------------------------
__global__ __launch_bounds__(384)
void outproj_kernel(const float* __restrict__ W_out,   // [D_, Q_]
                    const float* __restrict__ b_out,   // [Q_]
                    float* __restrict__ io)            // [BT_, *] od->out
{
    const int bt0 = blockIdx.x * 4;
    const int tid = threadIdx.x;            // 0..383 == output q

    __shared__ float s_od[4][D_];
    #pragma unroll
    for (int r = 0; r < 4; ++r)
        s_od[r][tid] = io[(size_t)(bt0 + r) * D_ + tid];
    __syncthreads();

    const float bo = b_out[tid];
    float acc[4] = {bo, bo, bo, bo};

    #pragma unroll 4
    for (int d = 0; d < D_; ++d) {
        const float w = W_out[(size_t)d * Q_ + tid];
        #pragma unroll
        for (int r = 0; r < 4; ++r) acc[r] += s_od[r][d] * w;
    }
    #pragma unroll
    for (int r = 0; r < 4; ++r)
        io[(size_t)(bt0 + r) * Q_ + tid] = acc[r];
}

extern "C" void kernel_launch(void* const* d_in, const int* in_sizes, int n_in,
                              void* d_out, int out_size, void* d_ws, size_t ws_size,
                              hipStream_t stream) {
    const float* queries = (const float*)d_in[0];
    const float* patch   = (const float*)d_in[1];
    const float* W_in    = (const float*)d_in[2];
    const float* b_in    = (const float*)d_in[3];
    const float* W_out   = (const float*)d_in[4];
    const float* b_out   = (const float*)d_in[5];
    float* io = (float*)d_out;   // BT_*Q_ == BT_*D_ floats, reused as scratch

    qproj_kernel<<<dim3(BT_ / 4), dim3(384), 0, stream>>>(queries, W_in, b_in, io);
    scores_topk_kernel<<<dim3(BT_), dim3(1024), 0, stream>>>(patch, io);
    outproj_kernel<<<dim3(BT_ / 4), dim3(384), 0, stream>>>(W_out, b_out, io);
}

// Round 5
// 42.763 us; speedup vs baseline: 1.9827x; 1.9827x over previous
//
#include <hip/hip_runtime.h>
#include <math.h>

#define B_  16
#define T_  16
#define N_  256
#define D_  384
#define Q_  384
#define K_  16
#define BT_ (B_ * T_)

// 2 graph nodes, no d_ws. d_out ("io") doubles as qp scratch: K1 writes
// qp[bt] into io row bt; K2 reads its own row, then overwrites it with the
// final output (block-local, barrier-ordered, idempotent across replays).

// ---------------------------------------------------------------------------
// K1: qp[bt] = queries[bt] @ W_in + b_in.  256 blocks x 768 threads.
// thread (half, d): sums q in [half*192, half*192+192). 2-way split-K.
// ---------------------------------------------------------------------------
__global__ __launch_bounds__(768)
void qproj_kernel(const float* __restrict__ queries,  // [BT_, Q_]
                  const float* __restrict__ W_in,     // [Q_, D_]
                  const float* __restrict__ b_in,     // [D_]
                  float* __restrict__ io)             // [BT_, D_] (d_out)
{
    const int bt  = blockIdx.x;
    const int tid = threadIdx.x;            // 0..767

    __shared__ float s_q[Q_];
    __shared__ float s_part[2 * D_];

    if (tid < Q_) s_q[tid] = queries[(size_t)bt * Q_ + tid];
    __syncthreads();

    {
        const int half = tid >= D_;
        const int d    = tid - half * D_;
        const int q0   = half * (Q_ / 2);
        float acc = 0.f;
        #pragma unroll 8
        for (int q = q0; q < q0 + Q_ / 2; ++q)
            acc += s_q[q] * W_in[(size_t)q * D_ + d];
        s_part[tid] = acc;
    }
    __syncthreads();
    if (tid < D_)
        io[(size_t)bt * D_ + tid] = s_part[tid] + s_part[tid + D_] + b_in[tid];
}

// ---------------------------------------------------------------------------
// K2: per (b,t): scores -> softmax -> exact top-K -> weighted sum -> outproj.
// 256 blocks x 1024 threads. Reads qp row from io, writes final out over it.
// ---------------------------------------------------------------------------
__global__ __launch_bounds__(1024)
void fused_kernel(const float* __restrict__ patch,   // [BT_, N_, D_]
                  const float* __restrict__ W_out,   // [D_, Q_]
                  const float* __restrict__ b_out,   // [Q_]
                  float* __restrict__ io)            // [BT_, *] qp -> out
{
    const int bt   = blockIdx.x;
    const int tid  = threadIdx.x;       // 0..1023
    const int lane = tid & 63;
    const int wave = tid >> 6;          // 0..15

    __shared__ float s_qp[D_];
    __shared__ float s_sc[N_];
    __shared__ int   s_cnt4[N_][4];
    __shared__ float s_red[4];
    __shared__ float s_red2[4][2];
    __shared__ float s_w[K_];
    __shared__ int   s_ix[K_];
    __shared__ float s_part[2 * D_];
    __shared__ float s_od[D_];

    const float* __restrict__ ptile = patch + (size_t)bt * N_ * D_;

    if (tid < D_) s_qp[tid] = io[(size_t)bt * D_ + tid];
    __syncthreads();

    // ---- scores: 16 waves x 4 rows (16-lane groups) x 4 iters ----
    {
        const int g  = lane >> 4;       // 0..3
        const int sl = lane & 15;
        const float4* s_qp4 = reinterpret_cast<const float4*>(s_qp);
        #pragma unroll
        for (int it = 0; it < N_ / 64; ++it) {
            const int n = it * 64 + wave * 4 + g;
            const float* prow = ptile + (size_t)n * D_;
            float p = 0.f;
            #pragma unroll
            for (int c = 0; c < 6; ++c) {
                const float4 a = *reinterpret_cast<const float4*>(prow + c * 64 + 4 * sl);
                const float4 b = s_qp4[c * 16 + sl];
                p += a.x * b.x + a.y * b.y + a.z * b.z + a.w * b.w;
            }
            #pragma unroll
            for (int off = 8; off; off >>= 1)
                p += __shfl_xor(p, off, 16);
            if (sl == 0) s_sc[n] = p;   // TEMP == 1
        }
    }
    __syncthreads();

    // ---- block max (waves 0-3) + rank partial counts (all 1024 threads) ----
    if (tid < N_) {
        float v = s_sc[tid];
        #pragma unroll
        for (int off = 32; off; off >>= 1) v = fmaxf(v, __shfl_xor(v, off));
        if (lane == 0) s_red[wave] = v;
    }
    {
        const int i   = tid >> 2;       // 0..255
        const int sub = tid & 3;        // j in [sub*64, sub*64+64)
        const float si = s_sc[i];
        int c = 0;
        #pragma unroll 8
        for (int j = sub * 64; j < sub * 64 + 64; ++j) {
            const float sj = s_sc[j];
            c += (int)(sj > si) | ((int)(sj == si) & (int)(j < i));
        }
        s_cnt4[i][sub] = c;
    }
    __syncthreads();

    // ---- e, Z, SK (threads < 256) ----
    float e = 0.f;
    int   cnt = N_;
    if (tid < N_) {
        const float mx = fmaxf(fmaxf(s_red[0], s_red[1]), fmaxf(s_red[2], s_red[3]));
        cnt = s_cnt4[tid][0] + s_cnt4[tid][1] + s_cnt4[tid][2] + s_cnt4[tid][3];
        e = __expf(s_sc[tid] - mx);

        float z  = e;
        float sk = (cnt < K_) ? e : 0.f;
        #pragma unroll
        for (int off = 32; off; off >>= 1) {
            z  += __shfl_xor(z, off);
            sk += __shfl_xor(sk, off);
        }
        if (lane == 0) { s_red2[wave][0] = z; s_red2[wave][1] = sk; }
    }
    __syncthreads();

    // weight_i = softmax_i / (sum_topk + EPS) = e_i / (SK + EPS*Z)
    {
        const float Z  = s_red2[0][0] + s_red2[1][0] + s_red2[2][0] + s_red2[3][0];
        const float SK = s_red2[0][1] + s_red2[1][1] + s_red2[2][1] + s_red2[3][1];
        const float inv = 1.f / (SK + 1e-8f * Z);
        if (tid < N_ && cnt < K_) {
            s_ix[cnt] = tid;
            s_w[cnt]  = e * inv;
        }
    }
    __syncthreads();

    // ---- weighted sum over K rows: 768 threads, 2-way split over j ----
    if (tid < 2 * D_) {
        const int half = tid >= D_;
        const int d    = tid - half * D_;
        const int j0   = half * (K_ / 2);
        float acc = 0.f;
        #pragma unroll
        for (int j = j0; j < j0 + K_ / 2; ++j)
            acc += s_w[j] * ptile[(size_t)s_ix[j] * D_ + d];
        s_part[tid] = acc;
    }
    __syncthreads();
    if (tid < D_) s_od[tid] = s_part[tid] + s_part[tid + D_];
    __syncthreads();

    // ---- out-proj: 768 threads, 2-way split-K over d ----
    if (tid < 2 * Q_) {
        const int half = tid >= Q_;
        const int q    = tid - half * Q_;
        const int d0   = half * (D_ / 2);
        float acc = 0.f;
        #pragma unroll 8
        for (int d = d0; d < d0 + D_ / 2; ++d)
            acc += s_od[d] * W_out[(size_t)d * Q_ + q];
        s_part[tid] = acc;
    }
    __syncthreads();
    if (tid < Q_)
        io[(size_t)bt * Q_ + tid] = s_part[tid] + s_part[tid + Q_] + b_out[tid];
}

extern "C" void kernel_launch(void* const* d_in, const int* in_sizes, int n_in,
                              void* d_out, int out_size, void* d_ws, size_t ws_size,
                              hipStream_t stream) {
    const float* queries = (const float*)d_in[0];
    const float* patch   = (const float*)d_in[1];
    const float* W_in    = (const float*)d_in[2];
    const float* b_in    = (const float*)d_in[3];
    const float* W_out   = (const float*)d_in[4];
    const float* b_out   = (const float*)d_in[5];
    float* io = (float*)d_out;   // BT_*Q_ floats, reused as qp scratch

    qproj_kernel<<<dim3(BT_), dim3(768), 0, stream>>>(queries, W_in, b_in, io);
    fused_kernel<<<dim3(BT_), dim3(1024), 0, stream>>>(patch, W_out, b_out, io);
}